// Round 13
// baseline (108.936 us; speedup 1.0000x reference)
//
#include <hip/hip_runtime.h>
#include <hip/hip_bf16.h>

// attention scale folded with log2(e): softmax exp(x) = exp2(x * log2e)
#define ATT_SCALE_L2E 0.2550322540f   // 32^-0.5 * log2(e)

typedef __attribute__((ext_vector_type(8))) short bf16x8;
typedef __attribute__((ext_vector_type(4))) short bf16x4;
typedef __attribute__((ext_vector_type(4))) float f32x4;
typedef __attribute__((ext_vector_type(16))) float f32x16;
typedef __attribute__((ext_vector_type(4))) int i32x4;

#define MFMA16(a, b, c) __builtin_amdgcn_mfma_f32_16x16x32_bf16(a, b, c, 0, 0, 0)
#define MFMA32(a, b, c) __builtin_amdgcn_mfma_f32_32x32x16_bf16(a, b, c, 0, 0, 0)

__device__ inline short f2b(float f) {
    return __builtin_bit_cast(short, __float2bfloat16(f));
}

// packed f32x2 -> bf16x2 in one instruction
__device__ inline int cvt_pk(float a, float b) {
    int r;
    asm("v_cvt_pk_bf16_f32 %0, %1, %2" : "=v"(r) : "v"(a), "v"(b));
    return r;
}

// ---------------------------------------------------------------------------
// K0a: w_qkv fp32 -> bf16
// ---------------------------------------------------------------------------
__global__ __launch_bounds__(256) void wconv_k(const float* __restrict__ w,
                                               short* __restrict__ wb) {
    int i0 = (blockIdx.x * 256 + threadIdx.x) * 8;
    float4 lo = *(const float4*)(w + i0);
    float4 hi = *(const float4*)(w + i0 + 4);
    bf16x8 o;
    o[0] = f2b(lo.x); o[1] = f2b(lo.y); o[2] = f2b(lo.z); o[3] = f2b(lo.w);
    o[4] = f2b(hi.x); o[5] = f2b(hi.y); o[6] = f2b(hi.z); o[7] = f2b(hi.w);
    *(bf16x8*)(wb + i0) = o;
}

// ---------------------------------------------------------------------------
// K0b: fused downsample + transpose + bf16: xt[b][n][c]
// ---------------------------------------------------------------------------
__global__ __launch_bounds__(256) void xt_k(const float* __restrict__ x,
                                            short* __restrict__ xt) {
    int b = blockIdx.y;
    int t = threadIdx.x;
    int n = blockIdx.x * 32 + (t >> 3);
    const float* xb = x + (size_t)b * 1048576 + (n >> 5) * 128 + (n & 31) * 2;
    short* dst = xt + ((size_t)b * 1024 + n) * 256;
#pragma unroll
    for (int it = 0; it < 4; ++it) {
        int c = (t & 7) * 8 + it * 64;
        bf16x8 o;
#pragma unroll
        for (int j = 0; j < 8; ++j) o[j] = f2b(xb[(size_t)(c + j) * 4096]);
        *(bf16x8*)(dst + c) = o;
    }
}

// ---------------------------------------------------------------------------
// K1: QKV MFMA GEMM (LDS-free main loop), epilogue transpose (unchanged r11).
// ---------------------------------------------------------------------------
__global__ __launch_bounds__(256) void qkv_k(const short* __restrict__ wb,
                                             const short* __restrict__ xt,
                                             short* __restrict__ qt,
                                             short* __restrict__ ktr,
                                             short* __restrict__ vvr) {
    int b = blockIdx.x;
    int ntile = blockIdx.y * 128;
    int otile = blockIdx.z * 64;
    int t = threadIdx.x;
    int w = t >> 6, l = t & 63, g = l >> 4, li = l & 15;
    int oh = (w & 1) * 32, mh = (w >> 1) * 64;
    int o_base = otile + oh;
    int head = o_base / 96;
    int role = (o_base >> 5) % 3;  // 0=q 1=k 2=v
    size_t bh = (size_t)b * 8 + head;

    const short* arow = wb + (size_t)o_base * 256;
    const short* brow = xt + ((size_t)b * 1024 + ntile + mh) * 256;

    f32x4 zero = {0.f, 0.f, 0.f, 0.f};
    f32x4 acc[2][4];
#pragma unroll
    for (int og = 0; og < 2; ++og)
#pragma unroll
        for (int mg = 0; mg < 4; ++mg) acc[og][mg] = zero;

#pragma unroll
    for (int kc = 0; kc < 256; kc += 32) {
        bf16x8 af[2], bf_[4];
#pragma unroll
        for (int og = 0; og < 2; ++og)
            af[og] = *(const bf16x8*)(arow + (size_t)(og * 16 + li) * 256 + kc + 8 * g);
#pragma unroll
        for (int mg = 0; mg < 4; ++mg)
            bf_[mg] = *(const bf16x8*)(brow + (size_t)(mg * 16 + li) * 256 + kc + 8 * g);
#pragma unroll
        for (int og = 0; og < 2; ++og)
#pragma unroll
            for (int mg = 0; mg < 4; ++mg)
                acc[og][mg] = MFMA16(af[og], bf_[mg], acc[og][mg]);
    }

    __shared__ short Tl[4][32][64];
    short (*Tw)[64] = Tl[w];
    float sc = (role == 0) ? ATT_SCALE_L2E : 1.f;

#pragma unroll
    for (int og = 0; og < 2; ++og)
#pragma unroll
        for (int mg = 0; mg < 4; ++mg)
#pragma unroll
            for (int r = 0; r < 4; ++r) {
                int op = og * 16 + 4 * g + r;
                int qp = (op >> 3) & 3;
                Tw[op][(mg * 16 + li) ^ (qp << 4)] = f2b(acc[og][mg][r] * sc);
            }
    __syncthreads();

    if (role == 0) {
#pragma unroll
        for (int it = 0; it < 4; ++it) {
            int s = it * 64 + l;
            int dq = (l & 3) * 8;
            int n = s >> 2;
            int q2 = dq >> 3;
            bf16x8 vo;
#pragma unroll
            for (int j = 0; j < 8; ++j)
                vo[j] = Tw[dq + j][n ^ (q2 << 4)];
            *(bf16x8*)(qt + ((size_t)bh * 1024 + ntile + mh + n) * 32 + dq) = vo;
        }
    } else if (role == 1) {
        int base_jb = (ntile + mh) >> 5;
#pragma unroll
        for (int it = 0; it < 4; ++it) {
            int s = it * 64 + l;
            int il2 = s & 31;
            int combo = (s >> 5) & 3;
            int jbr = s >> 7;
            int dq = combo * 8;
            int n_rel = jbr * 32 + il2;
            bf16x8 vo;
#pragma unroll
            for (int j = 0; j < 8; ++j)
                vo[j] = Tw[dq + j][n_rel ^ (combo << 4)];
            *(bf16x8*)(ktr + (size_t)bh * 32768 +
                       (size_t)(base_jb + jbr) * 1024 + combo * 256 + il2 * 8) = vo;
        }
    } else {
        int base_jb = (ntile + mh) >> 5;
#pragma unroll
        for (int it = 0; it < 4; ++it) {
            int s = it * 64 + l;
            int il2 = s & 31;
            int combo = (s >> 5) & 3;
            int jbr = s >> 7;
            int pan = combo >> 1, hi2 = combo & 1;
            int q2 = (il2 >> 3) & 3;
            int bn = jbr * 32 + pan * 16 + 4 * hi2;
            bf16x8 vo;
#pragma unroll
            for (int j = 0; j < 4; ++j) vo[j] = Tw[il2][(bn + j) ^ (q2 << 4)];
#pragma unroll
            for (int j = 0; j < 4; ++j) vo[4 + j] = Tw[il2][(bn + 8 + j) ^ (q2 << 4)];
            *(bf16x8*)(vvr + (size_t)bh * 32768 +
                       (size_t)(base_jb + jbr) * 1024 + combo * 256 + il2 * 8) = vo;
        }
    }
}

// ---------------------------------------------------------------------------
// K2: attention (r11 core, verified). Output ao_t[b][n][c] via float4 stores.
// ---------------------------------------------------------------------------
__global__ __launch_bounds__(512) void attn_k(const short* __restrict__ qt,
                                              const short* __restrict__ ktr,
                                              const short* __restrict__ vvr,
                                              float* __restrict__ ao_t) {
    int bh = blockIdx.x;
    int b = bh >> 3, h = bh & 7;
    int t = threadIdx.x;
    int w = t >> 6, l = t & 63;
    int il = l & 31, hi = l >> 5;
    int wq = w & 3, jh = w >> 2;
    int ibase = blockIdx.y * 128 + wq * 32;

    const short* qtb = qt + (size_t)bh * 32768;
    const short* kbase = ktr + (size_t)bh * 32768 + jh * 16384 + hi * 256 + il * 8;
    const short* vbase = vvr + (size_t)bh * 32768 + jh * 16384 + hi * 256 + il * 8;

    bf16x8 qf0 = *(const bf16x8*)(qtb + (size_t)(ibase + il) * 32 + 8 * hi);
    bf16x8 qf1 = *(const bf16x8*)(qtb + (size_t)(ibase + il) * 32 + 16 + 8 * hi);

    f32x16 zero16 = {0.f,0.f,0.f,0.f,0.f,0.f,0.f,0.f,0.f,0.f,0.f,0.f,0.f,0.f,0.f,0.f};
    f32x16 oacc = zero16;
    float lr0 = 0.f, lr1 = 0.f, lr2 = 0.f, lr3 = 0.f;

#pragma unroll 2
    for (int jb = 0; jb < 16; ++jb) {
        const short* kp = kbase + (size_t)jb * 1024;
        const short* vp = vbase + (size_t)jb * 1024;
        bf16x8 kf0 = *(const bf16x8*)(kp);
        bf16x8 kf1 = *(const bf16x8*)(kp + 512);
        f32x16 s = MFMA32(kf0, qf0, zero16);
        s = MFMA32(kf1, qf1, s);

        float p[16];
#pragma unroll
        for (int r = 0; r < 16; ++r) p[r] = exp2f(s[r]);
        lr0 += p[0] + p[4] + p[8]  + p[12];
        lr1 += p[1] + p[5] + p[9]  + p[13];
        lr2 += p[2] + p[6] + p[10] + p[14];
        lr3 += p[3] + p[7] + p[11] + p[15];

        i32x4 fa, fb;
        fa[0] = cvt_pk(p[0], p[1]);   fa[1] = cvt_pk(p[2], p[3]);
        fa[2] = cvt_pk(p[4], p[5]);   fa[3] = cvt_pk(p[6], p[7]);
        fb[0] = cvt_pk(p[8], p[9]);   fb[1] = cvt_pk(p[10], p[11]);
        fb[2] = cvt_pk(p[12], p[13]); fb[3] = cvt_pk(p[14], p[15]);
        bf16x8 pfa = __builtin_bit_cast(bf16x8, fa);
        bf16x8 pfb = __builtin_bit_cast(bf16x8, fb);

        bf16x8 vfa = *(const bf16x8*)(vp);
        bf16x8 vfb = *(const bf16x8*)(vp + 512);
        oacc = MFMA32(vfa, pfa, oacc);
        oacc = MFMA32(vfb, pfb, oacc);
    }

    float lrun = (lr0 + lr1) + (lr2 + lr3);

    // ---- fp32 combine of the two j-halves through LDS ----
    __shared__ float OB[4][64][20];
    __shared__ float LB[4][32];

    if (jh == 1) {
#pragma unroll
        for (int r4 = 0; r4 < 4; ++r4) {
            float4 v = {oacc[r4 * 4], oacc[r4 * 4 + 1], oacc[r4 * 4 + 2], oacc[r4 * 4 + 3]};
            *(float4*)&OB[wq][l][r4 * 4] = v;
        }
        float tu = lrun + __shfl_xor(lrun, 32);
        if (hi == 0) LB[wq][il] = tu;
    }
    __syncthreads();
    if (jh == 0) {
#pragma unroll
        for (int r = 0; r < 16; ++r) oacc[r] += OB[wq][l][r];
        float tl = lrun + __shfl_xor(lrun, 32);
        float inv = 1.f / (tl + LB[wq][il]);

        // ao_t[b][n][c]: n = ibase+il, c = h*32 + 4hi + 8rr + j
        float* basep = ao_t + ((size_t)(b * 1024 + ibase + il)) * 256 + h * 32 + 4 * hi;
#pragma unroll
        for (int rr = 0; rr < 4; ++rr) {
            float4 v = {oacc[rr * 4 + 0] * inv, oacc[rr * 4 + 1] * inv,
                        oacc[rr * 4 + 2] * inv, oacc[rr * 4 + 3] * inv};
            *(float4*)(basep + 8 * rr) = v;
        }
    }
}

// ---------------------------------------------------------------------------
// K3: per-(b,c) partial sum/sumsq over 128-n chunks of ao_t (r2-verified form)
// ---------------------------------------------------------------------------
__global__ __launch_bounds__(256) void psum_k(const float* __restrict__ ao_t,
                                              float* __restrict__ p1,
                                              float* __restrict__ p2) {
    int nc = blockIdx.x, b = blockIdx.y, c = threadIdx.x;
    const float* base = ao_t + ((size_t)b * 1024 + nc * 128) * 256 + c;
    float s = 0.f, q = 0.f;
#pragma unroll 4
    for (int n = 0; n < 128; ++n) {
        float v = base[(size_t)n * 256];
        s += v; q += v * v;
    }
    int idx = (b * 8 + nc) * 256 + c;
    p1[idx] = s; p2[idx] = q;
}

// ---------------------------------------------------------------------------
// K4: per-batch LayerNorm stats + proj tables (stab, ktab)
// ---------------------------------------------------------------------------
__global__ __launch_bounds__(256) void stats_k(const float* __restrict__ p1,
                                               const float* __restrict__ p2,
                                               const float* __restrict__ wlp,
                                               const float* __restrict__ blp,
                                               const float* __restrict__ gamma,
                                               const float* __restrict__ beta,
                                               const float* __restrict__ wp,
                                               float* __restrict__ stab,
                                               float* __restrict__ ktab) {
    int b = blockIdx.x, c = threadIdx.x;
    float s = 0.f, q = 0.f;
    for (int nc = 0; nc < 8; ++nc) {
        s += p1[(b * 8 + nc) * 256 + c];
        q += p2[(b * 8 + nc) * 256 + c];
    }
    float w0 = wlp[c * 4], w1 = wlp[c * 4 + 1], w2 = wlp[c * 4 + 2], w3 = wlp[c * 4 + 3];
    float S1 = w0 + w1 + w2 + w3, S2 = w0 * w0 + w1 * w1 + w2 * w2 + w3 * w3;
    float bl = blp[c];
    float su = S1 * s + 4096.f * bl;
    float sq = S2 * q + 2.f * bl * S1 * s + 4096.f * bl * bl;
    __shared__ float rs_[256], rq_[256];
    __shared__ float mss[2];
    rs_[c] = su; rq_[c] = sq;
    __syncthreads();
    for (int o = 128; o > 0; o >>= 1) {
        if (c < o) { rs_[c] += rs_[c + o]; rq_[c] += rq_[c + o]; }
        __syncthreads();
    }
    if (c == 0) {
        const float N = 1048576.f;
        float mu = rs_[0] / N;
        float var = rq_[0] / N - mu * mu;
        mss[0] = mu;
        mss[1] = rsqrtf(var + 1e-5f);
    }
    __syncthreads();
    float mu = mss[0], rs = mss[1];

    float Ac = gamma[c] * rs;
    stab[(b * 4 + 0) * 256 + c] = Ac * w0;
    stab[(b * 4 + 1) * 256 + c] = Ac * w1;
    stab[(b * 4 + 2) * 256 + c] = Ac * w2;
    stab[(b * 4 + 3) * 256 + c] = Ac * w3;

    // ktab[b][o] = sum_c wp[o,c] * (gamma[c]*rs*(blp[c]-mu) + beta[c])
    int o = c;
    const float* wrow = wp + (size_t)o * 256;
    float acc = 0.f;
#pragma unroll 4
    for (int cc = 0; cc < 256; cc += 4) {
        float4 wv = *(const float4*)(wrow + cc);
        float4 gv = *(const float4*)(gamma + cc);
        float4 lv = *(const float4*)(blp + cc);
        float4 bv = *(const float4*)(beta + cc);
        acc += wv.x * (gv.x * rs * (lv.x - mu) + bv.x);
        acc += wv.y * (gv.y * rs * (lv.y - mu) + bv.y);
        acc += wv.z * (gv.z * rs * (lv.z - mu) + bv.z);
        acc += wv.w * (gv.w * rs * (lv.w - mu) + bv.w);
    }
    ktab[b * 256 + o] = acc;
}

// ---------------------------------------------------------------------------
// K5: projection GEMM, r11-skeleton (Bs LDS staging, 2 barriers/chunk) with
// in-register A (no As LDS) and contiguous B staging from ao_t[n][c]*stab.
// y = GEMM + ktab[o]. Grid (b, mt, ot): linear%8 = b -> per-XCD locality.
// ---------------------------------------------------------------------------
__global__ __launch_bounds__(256) void proj_k(const float* __restrict__ ao_t,
                                              const float* __restrict__ wp,
                                              const float* __restrict__ stab,
                                              const float* __restrict__ ktab,
                                              float* __restrict__ y) {
    int b = blockIdx.x;
    int mt = blockIdx.y;
    int otile = blockIdx.z * 64;
    int t = threadIdx.x;
    int w = t >> 6, l = t & 63, g = l >> 4, li = l & 15;
    int oh = (w >> 1) * 32, mh = (w & 1) * 64;

    __shared__ short Bs[128][40];

    // B-staging role: thread covers (m_local = t>>1, c-rel [sc, sc+16))
    int sm = t >> 1;
    int sc = (t & 1) * 16;
    int gm = mt * 128 + sm;
    int sn = (gm >> 7) * 32 + ((gm & 63) >> 1);
    int spq = ((gm >> 6) & 1) * 2 + (gm & 1);
    const float* sao = ao_t + ((size_t)b * 1024 + sn) * 256 + sc;
    const float* sst = stab + ((size_t)b * 4 + spq) * 256 + sc;

    const float* wrowf = wp + (size_t)(otile + oh) * 256;

    f32x4 zero = {0.f, 0.f, 0.f, 0.f};
    f32x4 acc[2][4];
#pragma unroll
    for (int og = 0; og < 2; ++og)
#pragma unroll
        for (int mg = 0; mg < 4; ++mg) acc[og][mg] = zero;

    for (int kc = 0; kc < 256; kc += 32) {
        // stage B tile: 16 bf16 per thread, contiguous 64B source reads
        int* dst = (int*)&Bs[sm][sc];
#pragma unroll
        for (int q4 = 0; q4 < 4; ++q4) {
            float4 av = *(const float4*)(sao + kc + q4 * 4);
            float4 sv = *(const float4*)(sst + kc + q4 * 4);
            dst[q4 * 2 + 0] = cvt_pk(av.x * sv.x, av.y * sv.y);
            dst[q4 * 2 + 1] = cvt_pk(av.z * sv.z, av.w * sv.w);
        }
        // A fragments in-register from w_proj
        bf16x8 af[2];
#pragma unroll
        for (int og = 0; og < 2; ++og) {
            const float* wr = wrowf + (size_t)(og * 16 + li) * 256 + kc + 8 * g;
            float4 x0 = *(const float4*)(wr);
            float4 x1 = *(const float4*)(wr + 4);
            i32x4 aw;
            aw[0] = cvt_pk(x0.x, x0.y); aw[1] = cvt_pk(x0.z, x0.w);
            aw[2] = cvt_pk(x1.x, x1.y); aw[3] = cvt_pk(x1.z, x1.w);
            af[og] = __builtin_bit_cast(bf16x8, aw);
        }
        __syncthreads();
        bf16x8 bf_[4];
#pragma unroll
        for (int mg = 0; mg < 4; ++mg)
            bf_[mg] = *(const bf16x8*)&Bs[mh + mg * 16 + li][8 * g];
#pragma unroll
        for (int og = 0; og < 2; ++og)
#pragma unroll
            for (int mg = 0; mg < 4; ++mg)
                acc[og][mg] = MFMA16(af[og], bf_[mg], acc[og][mg]);
        __syncthreads();
    }

#pragma unroll
    for (int og = 0; og < 2; ++og) {
#pragma unroll
        for (int r = 0; r < 4; ++r) {
            int o = otile + oh + og * 16 + 4 * g + r;
            float kv = ktab[b * 256 + o];
#pragma unroll
            for (int mg = 0; mg < 4; ++mg) {
                int m = mt * 128 + mh + mg * 16 + li;
                y[((size_t)b * 256 + o) * 4096 + m] = acc[og][mg][r] + kv;
            }
        }
    }
}

extern "C" void kernel_launch(void* const* d_in, const int* in_sizes, int n_in,
                              void* d_out, int out_size, void* d_ws, size_t ws_size,
                              hipStream_t stream) {
    const float* x      = (const float*)d_in[0];
    const float* w_qkv  = (const float*)d_in[1];
    const float* w_lp   = (const float*)d_in[2];
    const float* b_lp   = (const float*)d_in[3];
    const float* gamma  = (const float*)d_in[4];
    const float* beta   = (const float*)d_in[5];
    const float* w_proj = (const float*)d_in[6];
    float* y = (float*)d_out;

    short* qt   = (short*)d_out;        // 2097152 shorts
    short* ktr  = qt + 2097152;
    short* vvr  = ktr + 2097152;
    short* xt   = vvr + 2097152;
    short* wbuf = xt + 2097152;

    float* ao_t  = (float*)d_ws;        // 2097152 floats [b][n][c]
    float* p1    = ao_t + 2097152;      // 16384
    float* p2    = p1 + 16384;          // 16384
    float* stab  = p2 + 16384;          // 8192 (8b x 4pq x 256c)
    float* ktab  = stab + 8192;         // 2048 (8b x 256o)

    wconv_k<<<96, 256, 0, stream>>>(w_qkv, wbuf);
    xt_k<<<dim3(32, 8), 256, 0, stream>>>(x, xt);
    qkv_k<<<dim3(8, 8, 12), 256, 0, stream>>>(wbuf, xt, qt, ktr, vvr);
    attn_k<<<dim3(64, 8), 512, 0, stream>>>(qt, ktr, vvr, ao_t);
    psum_k<<<dim3(8, 8), 256, 0, stream>>>(ao_t, p1, p2);
    stats_k<<<8, 256, 0, stream>>>(p1, p2, w_lp, b_lp, gamma, beta, w_proj, stab, ktab);
    proj_k<<<dim3(8, 32, 4), 256, 0, stream>>>(ao_t, w_proj, stab, ktab, y);
}

// Round 14
// 85.122 us; speedup vs baseline: 1.2798x; 1.2798x over previous
//
#include <hip/hip_runtime.h>
#include <hip/hip_bf16.h>

// attention scale folded with log2(e): softmax exp(x) = exp2(x * log2e)
#define ATT_SCALE_L2E 0.2550322540f   // 32^-0.5 * log2(e)

typedef __attribute__((ext_vector_type(8))) short bf16x8;
typedef __attribute__((ext_vector_type(4))) short bf16x4;
typedef __attribute__((ext_vector_type(4))) float f32x4;
typedef __attribute__((ext_vector_type(16))) float f32x16;
typedef __attribute__((ext_vector_type(4))) int i32x4;

#define MFMA16(a, b, c) __builtin_amdgcn_mfma_f32_16x16x32_bf16(a, b, c, 0, 0, 0)
#define MFMA32(a, b, c) __builtin_amdgcn_mfma_f32_32x32x16_bf16(a, b, c, 0, 0, 0)

__device__ inline short f2b(float f) {
    return __builtin_bit_cast(short, __float2bfloat16(f));
}

// packed f32x2 -> bf16x2 in one instruction
__device__ inline int cvt_pk(float a, float b) {
    int r;
    asm("v_cvt_pk_bf16_f32 %0, %1, %2" : "=v"(r) : "v"(a), "v"(b));
    return r;
}

// ---------------------------------------------------------------------------
// K0a: fp32 -> bf16 converter (used for w_qkv and w_proj)
// ---------------------------------------------------------------------------
__global__ __launch_bounds__(256) void wconv_k(const float* __restrict__ w,
                                               short* __restrict__ wb) {
    int i0 = (blockIdx.x * 256 + threadIdx.x) * 8;
    float4 lo = *(const float4*)(w + i0);
    float4 hi = *(const float4*)(w + i0 + 4);
    bf16x8 o;
    o[0] = f2b(lo.x); o[1] = f2b(lo.y); o[2] = f2b(lo.z); o[3] = f2b(lo.w);
    o[4] = f2b(hi.x); o[5] = f2b(hi.y); o[6] = f2b(hi.z); o[7] = f2b(hi.w);
    *(bf16x8*)(wb + i0) = o;
}

// ---------------------------------------------------------------------------
// K0b: fused downsample + transpose + bf16: xt[b][n][c]
// ---------------------------------------------------------------------------
__global__ __launch_bounds__(256) void xt_k(const float* __restrict__ x,
                                            short* __restrict__ xt) {
    int b = blockIdx.y;
    int t = threadIdx.x;
    int n = blockIdx.x * 32 + (t >> 3);
    const float* xb = x + (size_t)b * 1048576 + (n >> 5) * 128 + (n & 31) * 2;
    short* dst = xt + ((size_t)b * 1024 + n) * 256;
#pragma unroll
    for (int it = 0; it < 4; ++it) {
        int c = (t & 7) * 8 + it * 64;
        bf16x8 o;
#pragma unroll
        for (int j = 0; j < 8; ++j) o[j] = f2b(xb[(size_t)(c + j) * 4096]);
        *(bf16x8*)(dst + c) = o;
    }
}

// ---------------------------------------------------------------------------
// K1: QKV MFMA GEMM (LDS-free main loop), epilogue transpose (unchanged r11).
// ---------------------------------------------------------------------------
__global__ __launch_bounds__(256) void qkv_k(const short* __restrict__ wb,
                                             const short* __restrict__ xt,
                                             short* __restrict__ qt,
                                             short* __restrict__ ktr,
                                             short* __restrict__ vvr) {
    int b = blockIdx.x;
    int ntile = blockIdx.y * 128;
    int otile = blockIdx.z * 64;
    int t = threadIdx.x;
    int w = t >> 6, l = t & 63, g = l >> 4, li = l & 15;
    int oh = (w & 1) * 32, mh = (w >> 1) * 64;
    int o_base = otile + oh;
    int head = o_base / 96;
    int role = (o_base >> 5) % 3;  // 0=q 1=k 2=v
    size_t bh = (size_t)b * 8 + head;

    const short* arow = wb + (size_t)o_base * 256;
    const short* brow = xt + ((size_t)b * 1024 + ntile + mh) * 256;

    f32x4 zero = {0.f, 0.f, 0.f, 0.f};
    f32x4 acc[2][4];
#pragma unroll
    for (int og = 0; og < 2; ++og)
#pragma unroll
        for (int mg = 0; mg < 4; ++mg) acc[og][mg] = zero;

#pragma unroll
    for (int kc = 0; kc < 256; kc += 32) {
        bf16x8 af[2], bf_[4];
#pragma unroll
        for (int og = 0; og < 2; ++og)
            af[og] = *(const bf16x8*)(arow + (size_t)(og * 16 + li) * 256 + kc + 8 * g);
#pragma unroll
        for (int mg = 0; mg < 4; ++mg)
            bf_[mg] = *(const bf16x8*)(brow + (size_t)(mg * 16 + li) * 256 + kc + 8 * g);
#pragma unroll
        for (int og = 0; og < 2; ++og)
#pragma unroll
            for (int mg = 0; mg < 4; ++mg)
                acc[og][mg] = MFMA16(af[og], bf_[mg], acc[og][mg]);
    }

    __shared__ short Tl[4][32][64];
    short (*Tw)[64] = Tl[w];
    float sc = (role == 0) ? ATT_SCALE_L2E : 1.f;

#pragma unroll
    for (int og = 0; og < 2; ++og)
#pragma unroll
        for (int mg = 0; mg < 4; ++mg)
#pragma unroll
            for (int r = 0; r < 4; ++r) {
                int op = og * 16 + 4 * g + r;
                int qp = (op >> 3) & 3;
                Tw[op][(mg * 16 + li) ^ (qp << 4)] = f2b(acc[og][mg][r] * sc);
            }
    __syncthreads();

    if (role == 0) {
#pragma unroll
        for (int it = 0; it < 4; ++it) {
            int s = it * 64 + l;
            int dq = (l & 3) * 8;
            int n = s >> 2;
            int q2 = dq >> 3;
            bf16x8 vo;
#pragma unroll
            for (int j = 0; j < 8; ++j)
                vo[j] = Tw[dq + j][n ^ (q2 << 4)];
            *(bf16x8*)(qt + ((size_t)bh * 1024 + ntile + mh + n) * 32 + dq) = vo;
        }
    } else if (role == 1) {
        int base_jb = (ntile + mh) >> 5;
#pragma unroll
        for (int it = 0; it < 4; ++it) {
            int s = it * 64 + l;
            int il2 = s & 31;
            int combo = (s >> 5) & 3;
            int jbr = s >> 7;
            int dq = combo * 8;
            int n_rel = jbr * 32 + il2;
            bf16x8 vo;
#pragma unroll
            for (int j = 0; j < 8; ++j)
                vo[j] = Tw[dq + j][n_rel ^ (combo << 4)];
            *(bf16x8*)(ktr + (size_t)bh * 32768 +
                       (size_t)(base_jb + jbr) * 1024 + combo * 256 + il2 * 8) = vo;
        }
    } else {
        int base_jb = (ntile + mh) >> 5;
#pragma unroll
        for (int it = 0; it < 4; ++it) {
            int s = it * 64 + l;
            int il2 = s & 31;
            int combo = (s >> 5) & 3;
            int jbr = s >> 7;
            int pan = combo >> 1, hi2 = combo & 1;
            int q2 = (il2 >> 3) & 3;
            int bn = jbr * 32 + pan * 16 + 4 * hi2;
            bf16x8 vo;
#pragma unroll
            for (int j = 0; j < 4; ++j) vo[j] = Tw[il2][(bn + j) ^ (q2 << 4)];
#pragma unroll
            for (int j = 0; j < 4; ++j) vo[4 + j] = Tw[il2][(bn + 8 + j) ^ (q2 << 4)];
            *(bf16x8*)(vvr + (size_t)bh * 32768 +
                       (size_t)(base_jb + jbr) * 1024 + combo * 256 + il2 * 8) = vo;
        }
    }
}

// ---------------------------------------------------------------------------
// K2: attention (r11, verified at 78.8 total). Output ao2[b][c][n].
// ---------------------------------------------------------------------------
__global__ __launch_bounds__(512) void attn_k(const short* __restrict__ qt,
                                              const short* __restrict__ ktr,
                                              const short* __restrict__ vvr,
                                              float* __restrict__ ao2) {
    int bh = blockIdx.x;
    int b = bh >> 3, h = bh & 7;
    int t = threadIdx.x;
    int w = t >> 6, l = t & 63;
    int il = l & 31, hi = l >> 5;
    int wq = w & 3, jh = w >> 2;
    int ibase = blockIdx.y * 128 + wq * 32;

    const short* qtb = qt + (size_t)bh * 32768;
    const short* kbase = ktr + (size_t)bh * 32768 + jh * 16384 + hi * 256 + il * 8;
    const short* vbase = vvr + (size_t)bh * 32768 + jh * 16384 + hi * 256 + il * 8;

    bf16x8 qf0 = *(const bf16x8*)(qtb + (size_t)(ibase + il) * 32 + 8 * hi);
    bf16x8 qf1 = *(const bf16x8*)(qtb + (size_t)(ibase + il) * 32 + 16 + 8 * hi);

    f32x16 zero16 = {0.f,0.f,0.f,0.f,0.f,0.f,0.f,0.f,0.f,0.f,0.f,0.f,0.f,0.f,0.f,0.f};
    f32x16 oacc = zero16;
    float lr0 = 0.f, lr1 = 0.f, lr2 = 0.f, lr3 = 0.f;

#pragma unroll 2
    for (int jb = 0; jb < 16; ++jb) {
        const short* kp = kbase + (size_t)jb * 1024;
        const short* vp = vbase + (size_t)jb * 1024;
        bf16x8 kf0 = *(const bf16x8*)(kp);
        bf16x8 kf1 = *(const bf16x8*)(kp + 512);
        f32x16 s = MFMA32(kf0, qf0, zero16);
        s = MFMA32(kf1, qf1, s);

        float p[16];
#pragma unroll
        for (int r = 0; r < 16; ++r) p[r] = exp2f(s[r]);
        lr0 += p[0] + p[4] + p[8]  + p[12];
        lr1 += p[1] + p[5] + p[9]  + p[13];
        lr2 += p[2] + p[6] + p[10] + p[14];
        lr3 += p[3] + p[7] + p[11] + p[15];

        i32x4 fa, fb;
        fa[0] = cvt_pk(p[0], p[1]);   fa[1] = cvt_pk(p[2], p[3]);
        fa[2] = cvt_pk(p[4], p[5]);   fa[3] = cvt_pk(p[6], p[7]);
        fb[0] = cvt_pk(p[8], p[9]);   fb[1] = cvt_pk(p[10], p[11]);
        fb[2] = cvt_pk(p[12], p[13]); fb[3] = cvt_pk(p[14], p[15]);
        bf16x8 pfa = __builtin_bit_cast(bf16x8, fa);
        bf16x8 pfb = __builtin_bit_cast(bf16x8, fb);

        bf16x8 vfa = *(const bf16x8*)(vp);
        bf16x8 vfb = *(const bf16x8*)(vp + 512);
        oacc = MFMA32(vfa, pfa, oacc);
        oacc = MFMA32(vfb, pfb, oacc);
    }

    float lrun = (lr0 + lr1) + (lr2 + lr3);

    // ---- fp32 combine of the two j-halves through LDS ----
    __shared__ float OB[4][64][20];
    __shared__ float LB[4][32];

    if (jh == 1) {
#pragma unroll
        for (int r4 = 0; r4 < 4; ++r4) {
            float4 v = {oacc[r4 * 4], oacc[r4 * 4 + 1], oacc[r4 * 4 + 2], oacc[r4 * 4 + 3]};
            *(float4*)&OB[wq][l][r4 * 4] = v;
        }
        float tu = lrun + __shfl_xor(lrun, 32);
        if (hi == 0) LB[wq][il] = tu;
    }
    __syncthreads();
    if (jh == 0) {
#pragma unroll
        for (int r = 0; r < 16; ++r) oacc[r] += OB[wq][l][r];
        float tl = lrun + __shfl_xor(lrun, 32);
        float inv = 1.f / (tl + LB[wq][il]);

        float* base = ao2 + ((size_t)(b * 256 + h * 32)) * 1024 + ibase + il;
#pragma unroll
        for (int r = 0; r < 16; ++r) {
            int d = (r & 3) + 8 * (r >> 2) + 4 * hi;
            base[(size_t)d * 1024] = oacc[r] * inv;
        }
    }
}

// ---------------------------------------------------------------------------
// K3: per-(b,c) sum/sumsq of ao2 rows (contiguous 1024 floats). 1 wave/row.
// ---------------------------------------------------------------------------
__global__ __launch_bounds__(64) void psum_k(const float* __restrict__ ao2,
                                             float* __restrict__ p1,
                                             float* __restrict__ p2) {
    int row = blockIdx.x;
    const float* base = ao2 + (size_t)row * 1024;
    int l = threadIdx.x;
    float s = 0.f, q = 0.f;
#pragma unroll
    for (int t = 0; t < 4; ++t) {
        float4 v = *(const float4*)(base + l * 4 + t * 256);
        s += v.x + v.y + v.z + v.w;
        q += v.x * v.x + v.y * v.y + v.z * v.z + v.w * v.w;
    }
#pragma unroll
    for (int o = 1; o < 64; o <<= 1) {
        s += __shfl_xor(s, o);
        q += __shfl_xor(q, o);
    }
    if (l == 0) { p1[row] = s; p2[row] = q; }
}

// ---------------------------------------------------------------------------
// K4: per-batch LayerNorm stats (light, r11)
// ---------------------------------------------------------------------------
__global__ __launch_bounds__(256) void stats_k(const float* __restrict__ p1,
                                               const float* __restrict__ p2,
                                               const float* __restrict__ wlp,
                                               const float* __restrict__ blp,
                                               float* __restrict__ stats) {
    int b = blockIdx.x, c = threadIdx.x;
    float s = p1[b * 256 + c];
    float q = p2[b * 256 + c];
    float w0 = wlp[c * 4], w1 = wlp[c * 4 + 1], w2 = wlp[c * 4 + 2], w3 = wlp[c * 4 + 3];
    float S1 = w0 + w1 + w2 + w3, S2 = w0 * w0 + w1 * w1 + w2 * w2 + w3 * w3;
    float bl = blp[c];
    float su = S1 * s + 4096.f * bl;
    float sq = S2 * q + 2.f * bl * S1 * s + 4096.f * bl * bl;
    __shared__ float rs_[256], rq_[256];
    rs_[c] = su; rq_[c] = sq;
    __syncthreads();
    for (int o = 128; o > 0; o >>= 1) {
        if (c < o) { rs_[c] += rs_[c + o]; rq_[c] += rq_[c + o]; }
        __syncthreads();
    }
    if (c == 0) {
        const float N = 1048576.f;
        float mu = rs_[0] / N;
        float var = rq_[0] / N - mu * mu;
        stats[b] = mu;
        stats[8 + b] = rsqrtf(var + 1e-5f);
    }
}

// ---------------------------------------------------------------------------
// K5: MFMA projection GEMM (r11 skeleton). ONE change vs r11: A-fragments
// loaded directly from pre-converted bf16 wpb (qkv_k's proven load pattern)
// -> As LDS array and its staging removed. Bs staging byte-identical to r11.
// Grid (b, mt, otile): linear%8 = b -> per-XCD ao2[b] locality.
// ---------------------------------------------------------------------------
__global__ __launch_bounds__(256) void proj_k(const float* __restrict__ ao2,
                                              const short* __restrict__ wpb,
                                              const float* __restrict__ wlp,
                                              const float* __restrict__ blp,
                                              const float* __restrict__ gamma,
                                              const float* __restrict__ beta,
                                              const float* __restrict__ stats,
                                              float* __restrict__ y) {
    int b = blockIdx.x;
    int mt = blockIdx.y;
    int otile = blockIdx.z * 64;
    float mu = stats[b], rs = stats[8 + b];

    __shared__ short Bs[128][40];

    int t = threadIdx.x;
    int w = t >> 6, l = t & 63, g = l >> 4, li = l & 15;
    int oh = (w >> 1) * 32, mh = (w & 1) * 64;

    f32x4 zero = {0.f, 0.f, 0.f, 0.f};
    f32x4 acc[2][4];
#pragma unroll
    for (int og = 0; og < 2; ++og)
#pragma unroll
        for (int mg = 0; mg < 4; ++mg) acc[og][mg] = zero;

    int bc = t & 31, bm = (t >> 5) * 16;
    int p = t >> 7;
    int wbase = bm & 63;

    const short* arow = wpb + (size_t)(otile + oh) * 256;

    for (int kc = 0; kc < 256; kc += 32) {
        int c = kc + bc;
        float Ac = gamma[c] * rs;
        float Dc = Ac * (blp[c] - mu) + beta[c];
        float w0 = Ac * wlp[c * 4 + p * 2 + 0];
        float w1 = Ac * wlp[c * 4 + p * 2 + 1];
        const float* arow2 = ao2 + ((size_t)(b * 256 + c)) * 1024 + mt * 32 + (wbase >> 1);
        float4 a0 = *(const float4*)arow2;
        float4 a1 = *(const float4*)(arow2 + 4);
        float av[8] = {a0.x, a0.y, a0.z, a0.w, a1.x, a1.y, a1.z, a1.w};
#pragma unroll
        for (int k = 0; k < 8; ++k) {
            Bs[bm + 2 * k    ][bc] = f2b(w0 * av[k] + Dc);
            Bs[bm + 2 * k + 1][bc] = f2b(w1 * av[k] + Dc);
        }
        __syncthreads();
        bf16x8 af[2], bf_[4];
#pragma unroll
        for (int og = 0; og < 2; ++og)
            af[og] = *(const bf16x8*)(arow + (size_t)(og * 16 + li) * 256 + kc + 8 * g);
#pragma unroll
        for (int mg = 0; mg < 4; ++mg) bf_[mg] = *(const bf16x8*)&Bs[mh + mg * 16 + li][8 * g];
#pragma unroll
        for (int og = 0; og < 2; ++og)
#pragma unroll
            for (int mg = 0; mg < 4; ++mg) acc[og][mg] = MFMA16(af[og], bf_[mg], acc[og][mg]);
        __syncthreads();
    }

#pragma unroll
    for (int og = 0; og < 2; ++og) {
        int o = otile + oh + og * 16 + 4 * g;
#pragma unroll
        for (int mg = 0; mg < 4; ++mg) {
            int m = mt * 128 + mh + mg * 16 + li;
            float* yp = y + ((size_t)b * 256 + o) * 4096 + m;
#pragma unroll
            for (int r = 0; r < 4; ++r) yp[(size_t)r * 4096] = acc[og][mg][r];
        }
    }
}

extern "C" void kernel_launch(void* const* d_in, const int* in_sizes, int n_in,
                              void* d_out, int out_size, void* d_ws, size_t ws_size,
                              hipStream_t stream) {
    const float* x      = (const float*)d_in[0];
    const float* w_qkv  = (const float*)d_in[1];
    const float* w_lp   = (const float*)d_in[2];
    const float* b_lp   = (const float*)d_in[3];
    const float* gamma  = (const float*)d_in[4];
    const float* beta   = (const float*)d_in[5];
    const float* w_proj = (const float*)d_in[6];
    float* y = (float*)d_out;

    short* qt   = (short*)d_out;        // 2097152 shorts
    short* ktr  = qt + 2097152;
    short* vvr  = ktr + 2097152;
    short* xt   = vvr + 2097152;
    short* wbuf = xt + 2097152;

    float* ao2   = (float*)d_ws;        // 2097152 floats [b][c][n]
    float* p1    = ao2 + 2097152;       // 2048
    float* p2    = p1 + 2048;           // 2048
    float* stats = p2 + 2048;           // 16
    short* wpb   = (short*)(stats + 16); // 65536 shorts (w_proj bf16; in d_ws so
                                         // proj's y-writes can never race it)

    wconv_k<<<96, 256, 0, stream>>>(w_qkv, wbuf);
    wconv_k<<<32, 256, 0, stream>>>(w_proj, wpb);
    xt_k<<<dim3(32, 8), 256, 0, stream>>>(x, xt);
    qkv_k<<<dim3(8, 8, 12), 256, 0, stream>>>(wbuf, xt, qt, ktr, vvr);
    attn_k<<<dim3(64, 8), 512, 0, stream>>>(qt, ktr, vvr, ao2);
    psum_k<<<2048, 64, 0, stream>>>(ao2, p1, p2);
    stats_k<<<8, 256, 0, stream>>>(p1, p2, w_lp, b_lp, stats);
    proj_k<<<dim3(8, 32, 4), 256, 0, stream>>>(ao2, wpb, w_lp, b_lp, gamma, beta, stats, y);
}

// Round 15
// 80.278 us; speedup vs baseline: 1.3570x; 1.0603x over previous
//
#include <hip/hip_runtime.h>
#include <hip/hip_bf16.h>

// attention scale folded with log2(e): softmax exp(x) = exp2(x * log2e)
#define ATT_SCALE_L2E 0.2550322540f   // 32^-0.5 * log2(e)

typedef __attribute__((ext_vector_type(8))) short bf16x8;
typedef __attribute__((ext_vector_type(4))) short bf16x4;
typedef __attribute__((ext_vector_type(4))) float f32x4;
typedef __attribute__((ext_vector_type(16))) float f32x16;
typedef __attribute__((ext_vector_type(4))) int i32x4;

#define MFMA16(a, b, c) __builtin_amdgcn_mfma_f32_16x16x32_bf16(a, b, c, 0, 0, 0)
#define MFMA32(a, b, c) __builtin_amdgcn_mfma_f32_32x32x16_bf16(a, b, c, 0, 0, 0)

__device__ inline short f2b(float f) {
    return __builtin_bit_cast(short, __float2bfloat16(f));
}

// packed f32x2 -> bf16x2 in one instruction
__device__ inline int cvt_pk(float a, float b) {
    int r;
    asm("v_cvt_pk_bf16_f32 %0, %1, %2" : "=v"(r) : "v"(a), "v"(b));
    return r;
}

// ---------------------------------------------------------------------------
// K0a: w_qkv fp32 -> bf16
// ---------------------------------------------------------------------------
__global__ __launch_bounds__(256) void wconv_k(const float* __restrict__ w,
                                               short* __restrict__ wb) {
    int i0 = (blockIdx.x * 256 + threadIdx.x) * 8;
    float4 lo = *(const float4*)(w + i0);
    float4 hi = *(const float4*)(w + i0 + 4);
    bf16x8 o;
    o[0] = f2b(lo.x); o[1] = f2b(lo.y); o[2] = f2b(lo.z); o[3] = f2b(lo.w);
    o[4] = f2b(hi.x); o[5] = f2b(hi.y); o[6] = f2b(hi.z); o[7] = f2b(hi.w);
    *(bf16x8*)(wb + i0) = o;
}

// ---------------------------------------------------------------------------
// K0b: fused downsample + transpose + bf16: xt[b][n][c]
// ---------------------------------------------------------------------------
__global__ __launch_bounds__(256) void xt_k(const float* __restrict__ x,
                                            short* __restrict__ xt) {
    int b = blockIdx.y;
    int t = threadIdx.x;
    int n = blockIdx.x * 32 + (t >> 3);
    const float* xb = x + (size_t)b * 1048576 + (n >> 5) * 128 + (n & 31) * 2;
    short* dst = xt + ((size_t)b * 1024 + n) * 256;
#pragma unroll
    for (int it = 0; it < 4; ++it) {
        int c = (t & 7) * 8 + it * 64;
        bf16x8 o;
#pragma unroll
        for (int j = 0; j < 8; ++j) o[j] = f2b(xb[(size_t)(c + j) * 4096]);
        *(bf16x8*)(dst + c) = o;
    }
}

// ---------------------------------------------------------------------------
// K1: QKV MFMA GEMM (LDS-free main loop), epilogue transpose (r11, verified).
// ---------------------------------------------------------------------------
__global__ __launch_bounds__(256) void qkv_k(const short* __restrict__ wb,
                                             const short* __restrict__ xt,
                                             short* __restrict__ qt,
                                             short* __restrict__ ktr,
                                             short* __restrict__ vvr) {
    int b = blockIdx.x;
    int ntile = blockIdx.y * 128;
    int otile = blockIdx.z * 64;
    int t = threadIdx.x;
    int w = t >> 6, l = t & 63, g = l >> 4, li = l & 15;
    int oh = (w & 1) * 32, mh = (w >> 1) * 64;
    int o_base = otile + oh;
    int head = o_base / 96;
    int role = (o_base >> 5) % 3;  // 0=q 1=k 2=v
    size_t bh = (size_t)b * 8 + head;

    const short* arow = wb + (size_t)o_base * 256;
    const short* brow = xt + ((size_t)b * 1024 + ntile + mh) * 256;

    f32x4 zero = {0.f, 0.f, 0.f, 0.f};
    f32x4 acc[2][4];
#pragma unroll
    for (int og = 0; og < 2; ++og)
#pragma unroll
        for (int mg = 0; mg < 4; ++mg) acc[og][mg] = zero;

#pragma unroll
    for (int kc = 0; kc < 256; kc += 32) {
        bf16x8 af[2], bf_[4];
#pragma unroll
        for (int og = 0; og < 2; ++og)
            af[og] = *(const bf16x8*)(arow + (size_t)(og * 16 + li) * 256 + kc + 8 * g);
#pragma unroll
        for (int mg = 0; mg < 4; ++mg)
            bf_[mg] = *(const bf16x8*)(brow + (size_t)(mg * 16 + li) * 256 + kc + 8 * g);
#pragma unroll
        for (int og = 0; og < 2; ++og)
#pragma unroll
            for (int mg = 0; mg < 4; ++mg)
                acc[og][mg] = MFMA16(af[og], bf_[mg], acc[og][mg]);
    }

    __shared__ short Tl[4][32][64];
    short (*Tw)[64] = Tl[w];
    float sc = (role == 0) ? ATT_SCALE_L2E : 1.f;

#pragma unroll
    for (int og = 0; og < 2; ++og)
#pragma unroll
        for (int mg = 0; mg < 4; ++mg)
#pragma unroll
            for (int r = 0; r < 4; ++r) {
                int op = og * 16 + 4 * g + r;
                int qp = (op >> 3) & 3;
                Tw[op][(mg * 16 + li) ^ (qp << 4)] = f2b(acc[og][mg][r] * sc);
            }
    __syncthreads();

    if (role == 0) {
#pragma unroll
        for (int it = 0; it < 4; ++it) {
            int s = it * 64 + l;
            int dq = (l & 3) * 8;
            int n = s >> 2;
            int q2 = dq >> 3;
            bf16x8 vo;
#pragma unroll
            for (int j = 0; j < 8; ++j)
                vo[j] = Tw[dq + j][n ^ (q2 << 4)];
            *(bf16x8*)(qt + ((size_t)bh * 1024 + ntile + mh + n) * 32 + dq) = vo;
        }
    } else if (role == 1) {
        int base_jb = (ntile + mh) >> 5;
#pragma unroll
        for (int it = 0; it < 4; ++it) {
            int s = it * 64 + l;
            int il2 = s & 31;
            int combo = (s >> 5) & 3;
            int jbr = s >> 7;
            int dq = combo * 8;
            int n_rel = jbr * 32 + il2;
            bf16x8 vo;
#pragma unroll
            for (int j = 0; j < 8; ++j)
                vo[j] = Tw[dq + j][n_rel ^ (combo << 4)];
            *(bf16x8*)(ktr + (size_t)bh * 32768 +
                       (size_t)(base_jb + jbr) * 1024 + combo * 256 + il2 * 8) = vo;
        }
    } else {
        int base_jb = (ntile + mh) >> 5;
#pragma unroll
        for (int it = 0; it < 4; ++it) {
            int s = it * 64 + l;
            int il2 = s & 31;
            int combo = (s >> 5) & 3;
            int jbr = s >> 7;
            int pan = combo >> 1, hi2 = combo & 1;
            int q2 = (il2 >> 3) & 3;
            int bn = jbr * 32 + pan * 16 + 4 * hi2;
            bf16x8 vo;
#pragma unroll
            for (int j = 0; j < 4; ++j) vo[j] = Tw[il2][(bn + j) ^ (q2 << 4)];
#pragma unroll
            for (int j = 0; j < 4; ++j) vo[4 + j] = Tw[il2][(bn + 8 + j) ^ (q2 << 4)];
            *(bf16x8*)(vvr + (size_t)bh * 32768 +
                       (size_t)(base_jb + jbr) * 1024 + combo * 256 + il2 * 8) = vo;
        }
    }
}

// ---------------------------------------------------------------------------
// K2: attention (r11 core, verified) with 4-way in-block j-split.
// Block = 1024 threads = 16 waves: wave w = (i-chunk w&3, j-quarter w>>2),
// each wave handles 8 jb. fp32 combine through LDS (exact, one barrier,
// 3 writers + 1 reader per i-chunk). Zero extra HBM traffic vs r11.
// Grid (bh, itile): linear%8 = h -> per-XCD K/V locality. Output ao2[b][c][n].
// ---------------------------------------------------------------------------
__global__ __launch_bounds__(1024) void attn_k(const short* __restrict__ qt,
                                               const short* __restrict__ ktr,
                                               const short* __restrict__ vvr,
                                               float* __restrict__ ao2) {
    int bh = blockIdx.x;
    int b = bh >> 3, h = bh & 7;
    int t = threadIdx.x;
    int w = t >> 6, l = t & 63;
    int il = l & 31, hi = l >> 5;
    int wq = w & 3, jh = w >> 2;          // jh in 0..3
    int ibase = blockIdx.y * 128 + wq * 32;

    const short* qtb = qt + (size_t)bh * 32768;
    const short* kbase = ktr + (size_t)bh * 32768 + jh * 8192 + hi * 256 + il * 8;
    const short* vbase = vvr + (size_t)bh * 32768 + jh * 8192 + hi * 256 + il * 8;

    bf16x8 qf0 = *(const bf16x8*)(qtb + (size_t)(ibase + il) * 32 + 8 * hi);
    bf16x8 qf1 = *(const bf16x8*)(qtb + (size_t)(ibase + il) * 32 + 16 + 8 * hi);

    f32x16 zero16 = {0.f,0.f,0.f,0.f,0.f,0.f,0.f,0.f,0.f,0.f,0.f,0.f,0.f,0.f,0.f,0.f};
    f32x16 oacc = zero16;
    float lr0 = 0.f, lr1 = 0.f, lr2 = 0.f, lr3 = 0.f;

#pragma unroll 2
    for (int jb = 0; jb < 8; ++jb) {
        const short* kp = kbase + (size_t)jb * 1024;
        const short* vp = vbase + (size_t)jb * 1024;
        bf16x8 kf0 = *(const bf16x8*)(kp);
        bf16x8 kf1 = *(const bf16x8*)(kp + 512);
        f32x16 s = MFMA32(kf0, qf0, zero16);
        s = MFMA32(kf1, qf1, s);

        float p[16];
#pragma unroll
        for (int r = 0; r < 16; ++r) p[r] = exp2f(s[r]);
        lr0 += p[0] + p[4] + p[8]  + p[12];
        lr1 += p[1] + p[5] + p[9]  + p[13];
        lr2 += p[2] + p[6] + p[10] + p[14];
        lr3 += p[3] + p[7] + p[11] + p[15];

        i32x4 fa, fb;
        fa[0] = cvt_pk(p[0], p[1]);   fa[1] = cvt_pk(p[2], p[3]);
        fa[2] = cvt_pk(p[4], p[5]);   fa[3] = cvt_pk(p[6], p[7]);
        fb[0] = cvt_pk(p[8], p[9]);   fb[1] = cvt_pk(p[10], p[11]);
        fb[2] = cvt_pk(p[12], p[13]); fb[3] = cvt_pk(p[14], p[15]);
        bf16x8 pfa = __builtin_bit_cast(bf16x8, fa);
        bf16x8 pfb = __builtin_bit_cast(bf16x8, fb);

        bf16x8 vfa = *(const bf16x8*)(vp);
        bf16x8 vfb = *(const bf16x8*)(vp + 512);
        oacc = MFMA32(vfa, pfa, oacc);
        oacc = MFMA32(vfb, pfb, oacc);
    }

    float lrun = (lr0 + lr1) + (lr2 + lr3);

    // ---- fp32 combine of the four j-quarters through LDS ----
    __shared__ float OB[3][4][64][20];   // [writer jh-1][i-chunk][lane][16+pad]
    __shared__ float LB[3][4][32];

    if (jh != 0) {
        int s3 = jh - 1;
#pragma unroll
        for (int r4 = 0; r4 < 4; ++r4) {
            float4 v = {oacc[r4 * 4], oacc[r4 * 4 + 1], oacc[r4 * 4 + 2], oacc[r4 * 4 + 3]};
            *(float4*)&OB[s3][wq][l][r4 * 4] = v;
        }
        float tu = lrun + __shfl_xor(lrun, 32);
        if (hi == 0) LB[s3][wq][il] = tu;
    }
    __syncthreads();
    if (jh == 0) {
#pragma unroll
        for (int s3 = 0; s3 < 3; ++s3)
#pragma unroll
            for (int r = 0; r < 16; ++r) oacc[r] += OB[s3][wq][l][r];
        float tl = lrun + __shfl_xor(lrun, 32);
        float tot = tl + LB[0][wq][il] + LB[1][wq][il] + LB[2][wq][il];
        float inv = 1.f / tot;

        float* base = ao2 + ((size_t)(b * 256 + h * 32)) * 1024 + ibase + il;
#pragma unroll
        for (int r = 0; r < 16; ++r) {
            int d = (r & 3) + 8 * (r >> 2) + 4 * hi;
            base[(size_t)d * 1024] = oacc[r] * inv;
        }
    }
}

// ---------------------------------------------------------------------------
// K3: per-(b,c) sum/sumsq of ao2 rows (contiguous 1024 floats). 1 wave/row.
// ---------------------------------------------------------------------------
__global__ __launch_bounds__(64) void psum_k(const float* __restrict__ ao2,
                                             float* __restrict__ p1,
                                             float* __restrict__ p2) {
    int row = blockIdx.x;
    const float* base = ao2 + (size_t)row * 1024;
    int l = threadIdx.x;
    float s = 0.f, q = 0.f;
#pragma unroll
    for (int t = 0; t < 4; ++t) {
        float4 v = *(const float4*)(base + l * 4 + t * 256);
        s += v.x + v.y + v.z + v.w;
        q += v.x * v.x + v.y * v.y + v.z * v.z + v.w * v.w;
    }
#pragma unroll
    for (int o = 1; o < 64; o <<= 1) {
        s += __shfl_xor(s, o);
        q += __shfl_xor(q, o);
    }
    if (l == 0) { p1[row] = s; p2[row] = q; }
}

// ---------------------------------------------------------------------------
// K4: per-batch LayerNorm stats (light, r11)
// ---------------------------------------------------------------------------
__global__ __launch_bounds__(256) void stats_k(const float* __restrict__ p1,
                                               const float* __restrict__ p2,
                                               const float* __restrict__ wlp,
                                               const float* __restrict__ blp,
                                               float* __restrict__ stats) {
    int b = blockIdx.x, c = threadIdx.x;
    float s = p1[b * 256 + c];
    float q = p2[b * 256 + c];
    float w0 = wlp[c * 4], w1 = wlp[c * 4 + 1], w2 = wlp[c * 4 + 2], w3 = wlp[c * 4 + 3];
    float S1 = w0 + w1 + w2 + w3, S2 = w0 * w0 + w1 * w1 + w2 * w2 + w3 * w3;
    float bl = blp[c];
    float su = S1 * s + 4096.f * bl;
    float sq = S2 * q + 2.f * bl * S1 * s + 4096.f * bl * bl;
    __shared__ float rs_[256], rq_[256];
    rs_[c] = su; rq_[c] = sq;
    __syncthreads();
    for (int o = 128; o > 0; o >>= 1) {
        if (c < o) { rs_[c] += rs_[c + o]; rq_[c] += rq_[c + o]; }
        __syncthreads();
    }
    if (c == 0) {
        const float N = 1048576.f;
        float mu = rs_[0] / N;
        float var = rq_[0] / N - mu * mu;
        stats[b] = mu;
        stats[8 + b] = rsqrtf(var + 1e-5f);
    }
}

// ---------------------------------------------------------------------------
// K5: MFMA projection GEMM with fused upsample+LayerNorm B-operand (r11 exact).
// Grid (b, mt, otile): linear%8 = b -> per-XCD ao2[b] locality.
// ---------------------------------------------------------------------------
__global__ __launch_bounds__(256) void proj_k(const float* __restrict__ ao2,
                                              const float* __restrict__ wp,
                                              const float* __restrict__ wlp,
                                              const float* __restrict__ blp,
                                              const float* __restrict__ gamma,
                                              const float* __restrict__ beta,
                                              const float* __restrict__ stats,
                                              float* __restrict__ y) {
    int b = blockIdx.x;
    int mt = blockIdx.y;
    int otile = blockIdx.z * 64;
    float mu = stats[b], rs = stats[8 + b];

    __shared__ short As[64][40];
    __shared__ short Bs[128][40];

    int t = threadIdx.x;
    int w = t >> 6, l = t & 63, g = l >> 4, li = l & 15;
    int oh = (w >> 1) * 32, mh = (w & 1) * 64;

    f32x4 zero = {0.f, 0.f, 0.f, 0.f};
    f32x4 acc[2][4];
#pragma unroll
    for (int og = 0; og < 2; ++og)
#pragma unroll
        for (int mg = 0; mg < 4; ++mg) acc[og][mg] = zero;

    int so = t >> 2, sc = (t & 3) * 8;
    int bc = t & 31, bm = (t >> 5) * 16;
    int p = t >> 7;
    int wbase = bm & 63;

    for (int kc = 0; kc < 256; kc += 32) {
        const float* wrow = wp + (size_t)(otile + so) * 256 + kc + sc;
#pragma unroll
        for (int j = 0; j < 8; ++j) As[so][sc + j] = f2b(wrow[j]);
        int c = kc + bc;
        float Ac = gamma[c] * rs;
        float Dc = Ac * (blp[c] - mu) + beta[c];
        float w0 = Ac * wlp[c * 4 + p * 2 + 0];
        float w1 = Ac * wlp[c * 4 + p * 2 + 1];
        const float* arow = ao2 + ((size_t)(b * 256 + c)) * 1024 + mt * 32 + (wbase >> 1);
        float4 a0 = *(const float4*)arow;
        float4 a1 = *(const float4*)(arow + 4);
        float av[8] = {a0.x, a0.y, a0.z, a0.w, a1.x, a1.y, a1.z, a1.w};
#pragma unroll
        for (int k = 0; k < 8; ++k) {
            Bs[bm + 2 * k    ][bc] = f2b(w0 * av[k] + Dc);
            Bs[bm + 2 * k + 1][bc] = f2b(w1 * av[k] + Dc);
        }
        __syncthreads();
        bf16x8 af[2], bf_[4];
#pragma unroll
        for (int og = 0; og < 2; ++og) af[og] = *(const bf16x8*)&As[oh + og * 16 + li][8 * g];
#pragma unroll
        for (int mg = 0; mg < 4; ++mg) bf_[mg] = *(const bf16x8*)&Bs[mh + mg * 16 + li][8 * g];
#pragma unroll
        for (int og = 0; og < 2; ++og)
#pragma unroll
            for (int mg = 0; mg < 4; ++mg) acc[og][mg] = MFMA16(af[og], bf_[mg], acc[og][mg]);
        __syncthreads();
    }

#pragma unroll
    for (int og = 0; og < 2; ++og) {
        int o = otile + oh + og * 16 + 4 * g;
#pragma unroll
        for (int mg = 0; mg < 4; ++mg) {
            int m = mt * 128 + mh + mg * 16 + li;
            float* yp = y + ((size_t)b * 256 + o) * 4096 + m;
#pragma unroll
            for (int r = 0; r < 4; ++r) yp[(size_t)r * 4096] = acc[og][mg][r];
        }
    }
}

extern "C" void kernel_launch(void* const* d_in, const int* in_sizes, int n_in,
                              void* d_out, int out_size, void* d_ws, size_t ws_size,
                              hipStream_t stream) {
    const float* x      = (const float*)d_in[0];
    const float* w_qkv  = (const float*)d_in[1];
    const float* w_lp   = (const float*)d_in[2];
    const float* b_lp   = (const float*)d_in[3];
    const float* gamma  = (const float*)d_in[4];
    const float* beta   = (const float*)d_in[5];
    const float* w_proj = (const float*)d_in[6];
    float* y = (float*)d_out;

    short* qt   = (short*)d_out;        // 2097152 shorts
    short* ktr  = qt + 2097152;
    short* vvr  = ktr + 2097152;
    short* xt   = vvr + 2097152;
    short* wbuf = xt + 2097152;

    float* ao2   = (float*)d_ws;        // 2097152 floats [b][c][n]
    float* p1    = ao2 + 2097152;       // 2048
    float* p2    = p1 + 2048;           // 2048
    float* stats = p2 + 2048;           // 16

    wconv_k<<<96, 256, 0, stream>>>(w_qkv, wbuf);
    xt_k<<<dim3(32, 8), 256, 0, stream>>>(x, xt);
    qkv_k<<<dim3(8, 8, 12), 256, 0, stream>>>(wbuf, xt, qt, ktr, vvr);
    attn_k<<<dim3(64, 8), 1024, 0, stream>>>(qt, ktr, vvr, ao2);
    psum_k<<<2048, 64, 0, stream>>>(ao2, p1, p2);
    stats_k<<<8, 256, 0, stream>>>(p1, p2, w_lp, b_lp, stats);
    proj_k<<<dim3(8, 32, 4), 256, 0, stream>>>(ao2, w_proj, w_lp, b_lp, gamma, beta, stats, y);
}